// Round 9
// baseline (462.204 us; speedup 1.0000x reference)
//
#include <hip/hip_runtime.h>
#include <hip/hip_fp16.h>
#include <hip/hip_bf16.h>

// SlotAttention restructured:
//  dots = qs . x   with qs = LN(slots) @ (scale * Wq^T Wk)   (K never materialized)
//  updates folded:  gates_ih = (agg*fac) @ (Wih@Wv)^T        (V and upd never materialized)
// x = LN(inputs) stored once as fp16. fp32 accumulation. Output fp32.
// R8: tail = 6 kernels/iter, ~14us fixed cost each => dispatch-dominated.
// R9: tail = 2 row-complete kernels/iter: t_gates2 (pagg-reduce + gates GEMM
// + GRU + pre-norm) and t_mlp (mlp1 + mlp2 + residual + slot-LN + qs GEMV).
// K-major fp16 weights streamed coalesced (thread owns 4 cols, uint2/k).

#define BB 64
#define NN 4096
#define DD 256
#define NSL 8
#define NITER 3

__device__ __forceinline__ float wredsum(float v){
#pragma unroll
  for(int m=32;m;m>>=1) v += __shfl_xor(v, m, 64);
  return v;
}
__device__ __forceinline__ float2 u2f2(unsigned u){ __half2 h; __builtin_memcpy(&h,&u,4); return __half22float2(h); }
__device__ __forceinline__ float sigm(float v){ return 1.0f/(1.0f+__expf(-v)); }

union U4 { uint4 u; __half2 h[4]; };

// ---------------- prep: K-major fp16 weights + slots broadcast ----------------
__global__ __launch_bounds__(256) void k_prep(
    const float* __restrict__ Whh, const float* __restrict__ W1,
    const float* __restrict__ W2,  const float* __restrict__ sinit,
    __half* __restrict__ Wg, __half* __restrict__ W1t, __half* __restrict__ W2t,
    float* __restrict__ slots){
  for(int idx=blockIdx.x*256+threadIdx.x; idx<851968; idx+=gridDim.x*256){
    if(idx<196608){ int col=idx>>8, c=idx&255; Wg[(size_t)c*1536+768+col]=__float2half(Whh[idx]); }
    else if(idx<458752){ int k=idx-196608; int col=k>>8, c=k&255; W1t[(size_t)c*1024+col]=__float2half(W1[k]); }
    else if(idx<720896){ int k=idx-458752; int col=k>>10, c=k&1023; W2t[(size_t)c*256+col]=__float2half(W2[k]); }
    else { int k=idx-720896; slots[k]=sinit[k&2047]; }
  }
}

// ---------------- WC = Wih @ Wv  -> Wg cols 0..767 (K-major) ----------------
__global__ __launch_bounds__(256) void k_WC(const float* __restrict__ Wih, const float* __restrict__ Wv,
                                            __half* __restrict__ Wg){
  int col=blockIdx.x;  // 0..767
  int t=threadIdx.x;   // k 0..255
  __shared__ float wr[256];
  wr[t]=Wih[col*256+t];
  __syncthreads();
  float acc=0.f;
#pragma unroll 8
  for(int d=0;d<256;d++) acc += wr[d]*Wv[d*256+t];
  Wg[(size_t)t*1536+col]=__float2half(acc);
}

// ---------------- M2[c][e] = scale * (Wq^T Wk)[e][c]  (fp16) ----------------
__global__ __launch_bounds__(256) void k_M(const float* __restrict__ Wq, const float* __restrict__ Wk,
                                           __half* __restrict__ M2h){
  int c = blockIdx.x, e = threadIdx.x;
  float acc = 0.f;
#pragma unroll 8
  for(int d=0; d<256; d++) acc += Wq[d*256+e]*Wk[d*256+c];
  M2h[c*256+e] = __float2half(acc * 0.0625f);  // 256^-0.5
}

// ---------------- x = LN(inputs) -> fp16 ----------------
__global__ __launch_bounds__(256) void k_ln_x(const float* __restrict__ in, const float* __restrict__ g,
                                              const float* __restrict__ bbv, __half* __restrict__ x){
  int row  = blockIdx.x*4 + (threadIdx.x>>6);
  int lane = threadIdx.x&63;
  const float4 v = ((const float4*)(in + (size_t)row*DD))[lane];
  float s  = v.x+v.y+v.z+v.w;
  float ss = v.x*v.x+v.y*v.y+v.z*v.z+v.w*v.w;
  s = wredsum(s); ss = wredsum(ss);
  float m = s*(1.0f/256.0f);
  float r = rsqrtf(ss*(1.0f/256.0f) - m*m + 1e-5f);
  float4 gv = ((const float4*)g)[lane];
  float4 bv = ((const float4*)bbv)[lane];
  float y0=(v.x-m)*r*gv.x+bv.x, y1=(v.y-m)*r*gv.y+bv.y;
  float y2=(v.z-m)*r*gv.z+bv.z, y3=(v.w-m)*r*gv.w+bv.w;
  __half2 h0=__floats2half2_rn(y0,y1), h1=__floats2half2_rn(y2,y3);
  uint2 u; __builtin_memcpy(&u.x,&h0,4); __builtin_memcpy(&u.y,&h1,4);
  ((uint2*)(x + (size_t)row*DD))[lane] = u;
}

// ---------------- initial qs = LN(slots) @ M (once) ----------------
__global__ __launch_bounds__(256) void k_pre(const float* __restrict__ slots, const float* __restrict__ g,
                                             const float* __restrict__ bbv, const __half* __restrict__ M2h,
                                             float* __restrict__ qs){
  int row = blockIdx.x;      // 0..511
  int t = threadIdx.x;
  __shared__ __align__(16) float sn[256];
  __shared__ float red[8];
  float v = slots[row*256 + t];
  float s = wredsum(v), ss = wredsum(v*v);
  int wid=t>>6, lane=t&63;
  if(lane==0){ red[wid]=s; red[4+wid]=ss; }
  __syncthreads();
  float S  = red[0]+red[1]+red[2]+red[3];
  float SS = red[4]+red[5]+red[6]+red[7];
  float m = S*(1.0f/256.0f);
  float r = rsqrtf(SS*(1.0f/256.0f) - m*m + 1e-5f);
  sn[t] = (v-m)*r*g[t]+bbv[t];
  __syncthreads();
  const uint4* w4 = (const uint4*)(M2h + (size_t)t*256);
  float acc=0.f;
#pragma unroll 4
  for(int kk=0;kk<32;kk++){
    U4 w; w.u=w4[kk];
#pragma unroll
    for(int q=0;q<4;q++){
      float2 f=__half22float2(w.h[q]);
      acc += sn[kk*8+2*q]*f.x + sn[kk*8+2*q+1]*f.y;
    }
  }
  qs[row*256+t]=acc;
}

// ---------------- fused attention pass: dots+softmax -> w -> partial agg ----------------
__global__ __launch_bounds__(256) void k_att(const __half* __restrict__ x, const float* __restrict__ qs,
                                             float* __restrict__ pagg){
  int b = blockIdx.x>>4;
  int t = threadIdx.x;
  size_t j = (size_t)blockIdx.x*256 + t;
  __shared__ __align__(16) float qt[256][8];
  __shared__ __align__(16) float wl[256][8];
  __shared__ __align__(16) float aggl[4][2048];
  __shared__ float wsl[4][8];
  const float* qb = qs + b*2048;
  for(int e=t;e<2048;e+=256) qt[e&255][e>>8]=qb[e];
  __syncthreads();
  const uint4* xr = (const uint4*)(x + j*DD);
  float pd[8]={0,0,0,0,0,0,0,0};
#pragma unroll 2
  for(int ch=0; ch<32; ch++){
    uint4 u = xr[ch];
    float2 f0=u2f2(u.x), f1=u2f2(u.y), f2=u2f2(u.z), f3=u2f2(u.w);
    float xv[8]={f0.x,f0.y,f1.x,f1.y,f2.x,f2.y,f3.x,f3.y};
    int c0=ch*8;
#pragma unroll
    for(int cc=0;cc<8;cc++){
      const float4* qp=(const float4*)&qt[c0+cc][0];
      float4 qa=qp[0], qc=qp[1];
      float xvv=xv[cc];
      pd[0]+=qa.x*xvv; pd[1]+=qa.y*xvv; pd[2]+=qa.z*xvv; pd[3]+=qa.w*xvv;
      pd[4]+=qc.x*xvv; pd[5]+=qc.y*xvv; pd[6]+=qc.z*xvv; pd[7]+=qc.w*xvv;
    }
  }
  float mx=pd[0];
#pragma unroll
  for(int i=1;i<8;i++) mx=fmaxf(mx,pd[i]);
  float ev[8]; float ssum=0.f;
#pragma unroll
  for(int i=0;i<8;i++){ ev[i]=__expf(pd[i]-mx); ssum+=ev[i]; }
  float inv=1.0f/ssum;
#pragma unroll
  for(int i=0;i<8;i++) wl[t][i]=ev[i]*inv+1e-5f;
  __syncthreads();
  int wid=t>>6, lane=t&63;
  float acc[8][4];
#pragma unroll
  for(int i=0;i<8;i++){ acc[i][0]=0;acc[i][1]=0;acc[i][2]=0;acc[i][3]=0; }
  float ws[8]={0,0,0,0,0,0,0,0};
  for(int r=0;r<64;r++){
    int jl = wid*64 + r;
    uint2 u = ((const uint2*)(x + ((size_t)blockIdx.x*256 + jl)*DD))[lane];
    float2 f01=u2f2(u.x), f23=u2f2(u.y);
    const float4* wp=(const float4*)&wl[jl][0];
    float4 wa=wp[0], wb_=wp[1];
    float wv[8]={wa.x,wa.y,wa.z,wa.w,wb_.x,wb_.y,wb_.z,wb_.w};
    float xv[4]={f01.x,f01.y,f23.x,f23.y};
#pragma unroll
    for(int i=0;i<8;i++){
      acc[i][0]+=wv[i]*xv[0]; acc[i][1]+=wv[i]*xv[1];
      acc[i][2]+=wv[i]*xv[2]; acc[i][3]+=wv[i]*xv[3];
      ws[i]+=wv[i];
    }
  }
#pragma unroll
  for(int i=0;i<8;i++){
    float4 st={acc[i][0],acc[i][1],acc[i][2],acc[i][3]};
    *((float4*)&aggl[wid][i*256 + lane*4])=st;
  }
  if(lane==0){
#pragma unroll
    for(int i=0;i<8;i++) wsl[wid][i]=ws[i];
  }
  __syncthreads();
  float* pb = pagg + (size_t)blockIdx.x*2064;
  for(int e=t;e<2048;e+=256) pb[e]=aggl[0][e]+aggl[1][e]+aggl[2][e]+aggl[3][e];
  if(t<8) pb[2048+t]=wsl[0][t]+wsl[1][t]+wsl[2][t]+wsl[3][t];
}

// ---------------- t_gates2: pagg-reduce + fac + gates GEMM + GRU + MLP pre-norm ----------------
// grid 256 (2 slot-rows each), 512 threads
__global__ __launch_bounds__(512) void t_gates2(
    const float* __restrict__ pagg, const float* __restrict__ slots_in,
    const __half* __restrict__ Wg, const float* __restrict__ bih, const float* __restrict__ bhh,
    const float* __restrict__ lm_g, const float* __restrict__ lm_b,
    float* __restrict__ hb, __half* __restrict__ ysh){
  int row0=blockIdx.x*2;
  int b=row0>>3, i0=row0&7;       // rows row0,row0+1 always same batch (row0 even)
  int t=threadIdx.x;
  int r=t>>8, c=t&255;
  __shared__ float AS[4][256];    // rows 0,1: agg*fac ; rows 2,3: slots
  __shared__ __align__(16) float gl[2][1536];
  __shared__ float fac[2];
  __shared__ float redS[2][4], redQ[2][4];
  const float* pb = pagg + (size_t)b*16*2064;
  {
    float s=0.f;
#pragma unroll
    for(int ch=0;ch<16;ch++) s += pb[ch*2064 + (i0+r)*256 + c];
    AS[r][c]=s;
    AS[2+r][c]=slots_in[(size_t)(row0+r)*256+c];
  }
  if(t<2){
    float s=0.f;
#pragma unroll
    for(int ch=0;ch<16;ch++) s += pb[ch*2064 + 2048 + i0 + t];
    fac[t]=4096.0f/s;
  }
  __syncthreads();
  AS[r][c] *= fac[r];
  __syncthreads();
  // gates GEMM: 384 active threads x 4 cols, K=256, coalesced uint2 weight stream
  if(t<384){
    int c0=t*4;
    bool ih = c0<768;
    const float* X0 = ih? AS[0] : AS[2];
    const float* X1 = ih? AS[1] : AS[3];
    const __half* wb = Wg + c0;
    float a00=0,a01=0,a02=0,a03=0, a10=0,a11=0,a12=0,a13=0;
#pragma unroll 8
    for(int k=0;k<256;k++){
      uint2 u = *(const uint2*)(wb + (size_t)k*1536);
      float2 f0=u2f2(u.x), f1=u2f2(u.y);
      float x0=X0[k], x1=X1[k];
      a00+=x0*f0.x; a01+=x0*f0.y; a02+=x0*f1.x; a03+=x0*f1.y;
      a10+=x1*f0.x; a11+=x1*f0.y; a12+=x1*f1.x; a13+=x1*f1.y;
    }
    const float* bb = ih? bih : bhh;
    int bc = ih? c0 : c0-768;
    float4 bv=*(const float4*)&bb[bc];
    gl[0][c0]=a00+bv.x; gl[0][c0+1]=a01+bv.y; gl[0][c0+2]=a02+bv.z; gl[0][c0+3]=a03+bv.w;
    gl[1][c0]=a10+bv.x; gl[1][c0+1]=a11+bv.y; gl[1][c0+2]=a12+bv.z; gl[1][c0+3]=a13+bv.w;
  }
  __syncthreads();
  // GRU nonlinearity + pre-norm
  {
    float gir=gl[r][c], giz=gl[r][256+c], gin=gl[r][512+c];
    float ghr=gl[r][768+c], ghz=gl[r][1024+c], ghn=gl[r][1280+c];
    float hp=AS[2+r][c];
    float rr=sigm(gir+ghr), z=sigm(giz+ghz);
    float n=tanhf(gin+rr*ghn);
    float hv=(1.0f-z)*n+z*hp;
    hb[(size_t)(row0+r)*256+c]=hv;
    float s=wredsum(hv), ss=wredsum(hv*hv);
    if((t&63)==0){ redS[r][(t>>6)&3]=s; redQ[r][(t>>6)&3]=ss; }
    __syncthreads();
    float S_=redS[r][0]+redS[r][1]+redS[r][2]+redS[r][3];
    float SS=redQ[r][0]+redQ[r][1]+redQ[r][2]+redQ[r][3];
    float m=S_*(1.0f/256.0f);
    float rs=rsqrtf(SS*(1.0f/256.0f)-m*m+1e-5f);
    ysh[(size_t)(row0+r)*256+c]=__float2half((hv-m)*rs*lm_g[c]+lm_b[c]);
  }
}

// ---------------- t_mlp: mlp1 + mlp2 + residual + slot-LN + qs ----------------
// grid 256 (2 slot-rows each), 512 threads
__global__ __launch_bounds__(512) void t_mlp(
    const float* __restrict__ hb, const __half* __restrict__ ysg,
    const __half* __restrict__ W1t, const float* __restrict__ b1,
    const __half* __restrict__ W2t, const float* __restrict__ b2,
    const float* __restrict__ ls_g, const float* __restrict__ ls_b,
    const __half* __restrict__ M2h,
    float* __restrict__ dst, float* __restrict__ qs, int last){
  int row0=blockIdx.x*2;
  int t=threadIdx.x;
  int r=t>>8, c=t&255;
  __shared__ float ys[2][256];
  __shared__ __align__(16) float pz[2][2][1024];  // [ks][row][col]
  __shared__ __align__(16) float z1[2][1024];
  __shared__ float pm[2][4][256];                 // [row][ks4][col]
  __shared__ float redS[2][4], redQ[2][4];
  ys[r][c]=__half2float(ysg[(size_t)(row0+r)*256+c]);
  __syncthreads();
  // mlp1 partials: ks=r (K half), cq=c (4 cols each), K=128
  {
    int c0=c*4;
    const __half* wb = W1t + (size_t)r*128*1024 + c0;
    float a00=0,a01=0,a02=0,a03=0, a10=0,a11=0,a12=0,a13=0;
#pragma unroll 8
    for(int k=0;k<128;k++){
      uint2 u=*(const uint2*)(wb + (size_t)k*1024);
      float2 f0=u2f2(u.x), f1=u2f2(u.y);
      float x0=ys[0][r*128+k], x1=ys[1][r*128+k];
      a00+=x0*f0.x; a01+=x0*f0.y; a02+=x0*f1.x; a03+=x0*f1.y;
      a10+=x1*f0.x; a11+=x1*f0.y; a12+=x1*f1.x; a13+=x1*f1.y;
    }
    pz[r][0][c0]=a00; pz[r][0][c0+1]=a01; pz[r][0][c0+2]=a02; pz[r][0][c0+3]=a03;
    pz[r][1][c0]=a10; pz[r][1][c0+1]=a11; pz[r][1][c0+2]=a12; pz[r][1][c0+3]=a13;
  }
  __syncthreads();
  for(int idx=t; idx<2048; idx+=512){
    int rr2=idx>>10, cc=idx&1023;
    float v=pz[0][rr2][cc]+pz[1][rr2][cc]+b1[cc];
    z1[rr2][cc]= v>0.f? v : 0.01f*v;
  }
  __syncthreads();
  // mlp2 partials: 256 active threads (ks4=t>>6, cg=t&63), both rows, K=256 each
  if(t<256){
    int ks4=t>>6, cg=t&63;
    int c0=cg*4;
    const __half* wb = W2t + (size_t)ks4*256*256 + c0;
    float a00=0,a01=0,a02=0,a03=0, a10=0,a11=0,a12=0,a13=0;
#pragma unroll 8
    for(int k=0;k<256;k++){
      uint2 u=*(const uint2*)(wb + (size_t)k*256);
      float2 f0=u2f2(u.x), f1=u2f2(u.y);
      float x0=z1[0][ks4*256+k], x1=z1[1][ks4*256+k];
      a00+=x0*f0.x; a01+=x0*f0.y; a02+=x0*f1.x; a03+=x0*f1.y;
      a10+=x1*f0.x; a11+=x1*f0.y; a12+=x1*f1.x; a13+=x1*f1.y;
    }
    pm[0][ks4][c0]=a00; pm[0][ks4][c0+1]=a01; pm[0][ks4][c0+2]=a02; pm[0][ks4][c0+3]=a03;
    pm[1][ks4][c0]=a10; pm[1][ks4][c0+1]=a11; pm[1][ks4][c0+2]=a12; pm[1][ks4][c0+3]=a13;
  }
  __syncthreads();
  float s = hb[(size_t)(row0+r)*256+c] + pm[r][0][c]+pm[r][1][c]+pm[r][2][c]+pm[r][3][c] + b2[c];
  dst[(size_t)(row0+r)*256+c]=s;
  if(last) return;
  // slot-LN + qs for next iter
  float su=wredsum(s), sq=wredsum(s*s);
  if((t&63)==0){ redS[r][(t>>6)&3]=su; redQ[r][(t>>6)&3]=sq; }
  __syncthreads();
  float S_=redS[r][0]+redS[r][1]+redS[r][2]+redS[r][3];
  float SS=redQ[r][0]+redQ[r][1]+redQ[r][2]+redQ[r][3];
  float m=S_*(1.0f/256.0f);
  float rs=rsqrtf(SS*(1.0f/256.0f)-m*m+1e-5f);
  ys[r][c]=(s-m)*rs*ls_g[c]+ls_b[c];
  __syncthreads();
  {
    const uint4* m4=(const uint4*)(M2h+(size_t)c*256);
    float acc=0.f;
#pragma unroll 4
    for(int kk=0;kk<32;kk++){
      U4 w; w.u=m4[kk];
#pragma unroll
      for(int q=0;q<4;q++){
        float2 f=__half22float2(w.h[q]);
        acc += ys[r][kk*8+2*q]*f.x + ys[r][kk*8+2*q+1]*f.y;
      }
    }
    qs[(size_t)(row0+r)*256+c]=acc;
  }
}

extern "C" void kernel_launch(void* const* d_in, const int* in_sizes, int n_in,
                              void* d_out, int out_size, void* d_ws, size_t ws_size,
                              hipStream_t stream){
  const float* inputs=(const float*)d_in[0];
  const float* sinit =(const float*)d_in[1];
  const float* Wq =(const float*)d_in[2];
  const float* Wk =(const float*)d_in[3];
  const float* Wv =(const float*)d_in[4];
  const float* Wih=(const float*)d_in[5];
  const float* Whh=(const float*)d_in[6];
  const float* bih=(const float*)d_in[7];
  const float* bhh=(const float*)d_in[8];
  const float* lin_g=(const float*)d_in[9];
  const float* lin_b=(const float*)d_in[10];
  const float* ls_g=(const float*)d_in[11];
  const float* ls_b=(const float*)d_in[12];
  const float* lm_g=(const float*)d_in[13];
  const float* lm_b=(const float*)d_in[14];
  const float* W1=(const float*)d_in[15];
  const float* b1=(const float*)d_in[16];
  const float* W2=(const float*)d_in[17];
  const float* b2=(const float*)d_in[18];

  char* w=(char*)d_ws;
  __half* x    =(__half*)w; w += (size_t)BB*NN*DD*2;        // 134.2 MB
  float* qs    =(float*)w;  w += 512*256*4;
  float* slots =(float*)w;  w += 512*256*4;
  float* pagg  =(float*)w;  w += (size_t)1024*2064*4;       // 8.45 MB
  __half* M2h  =(__half*)w; w += 256*256*2;
  __half* Wg   =(__half*)w; w += 256*1536*2;
  __half* W1t  =(__half*)w; w += 256*1024*2;
  __half* W2t  =(__half*)w; w += 1024*256*2;
  float* hb    =(float*)w;  w += 512*256*4;
  __half* ysh  =(__half*)w; w += 512*256*2;

  hipLaunchKernelGGL(k_prep, dim3(1664), dim3(256), 0, stream,
                     Whh, W1, W2, sinit, Wg, W1t, W2t, slots);
  hipLaunchKernelGGL(k_WC,   dim3(768),  dim3(256), 0, stream, Wih, Wv, Wg);
  hipLaunchKernelGGL(k_M,    dim3(256),  dim3(256), 0, stream, Wq, Wk, M2h);
  hipLaunchKernelGGL(k_ln_x, dim3(65536),dim3(256), 0, stream, inputs, lin_g, lin_b, x);
  hipLaunchKernelGGL(k_pre,  dim3(512),  dim3(256), 0, stream, slots, ls_g, ls_b, M2h, qs);
  for(int it=0; it<NITER; ++it){
    int last = (it==NITER-1);
    float* dst = last ? (float*)d_out : slots;
    hipLaunchKernelGGL(k_att,    dim3(1024), dim3(256), 0, stream, x, qs, pagg);
    hipLaunchKernelGGL(t_gates2, dim3(256),  dim3(512), 0, stream, pagg, slots, Wg, bih, bhh,
                       lm_g, lm_b, hb, ysh);
    hipLaunchKernelGGL(t_mlp,    dim3(256),  dim3(512), 0, stream, hb, ysh, W1t, b1, W2t, b2,
                       ls_g, ls_b, M2h, dst, qs, last);
  }
}